// Round 13
// baseline (39.710 us; speedup 1.0000x reference)
//
#include <hip/hip_runtime.h>
#include <hip/hip_bf16.h>

namespace {

typedef __attribute__((ext_vector_type(8))) short short8;  // 8 bf16 = 4 VGPR
typedef __attribute__((ext_vector_type(4))) float f32x4;   // MFMA accumulator

constexpr int kNB = 256;   // batch
constexpr int kNQ = 16;    // queries per batch
constexpr int kNK = 200;   // keys per batch
constexpr int kDK = 64;    // key/query feature size
constexpr int kNH = 128;   // hidden
constexpr int kThreads = 1024;  // 16 waves
constexpr int kS = 132;         // Ek row stride in floats
constexpr float kNeg = -1000000000.0f;
constexpr float kC2 = 2.8853900817779268f;  // 2*log2(e): exp(2x)=exp2(kC2*x)

constexpr int kKhFloats = kNK * kS;   // 105600 B
constexpr int kScFloats = kNQ * kNK;  // 12800 B
constexpr int kQhFloats = kNQ * kNH;  //  8192 B
constexpr size_t kSmemBytes =
    (size_t)(kKhFloats + kScFloats + kQhFloats) * sizeof(float);  // 126592 B

__device__ __forceinline__ float exp2_hw(float x) {
#if defined(__has_builtin)
# if __has_builtin(__builtin_amdgcn_exp2f)
  return __builtin_amdgcn_exp2f(x);
# else
  return __expf(x * 0.69314718055994531f);
# endif
#else
  return __expf(x * 0.69314718055994531f);
#endif
}

template <int CTRL>
__device__ __forceinline__ float dpp_add(float v) {
  int sw = __builtin_amdgcn_update_dpp(0, __float_as_int(v), CTRL, 0xF, 0xF, true);
  return v + __int_as_float(sw);
}

// split-bf16 via hip casts (compiler packs v_cvt_pk_bf16_f32)
__device__ __forceinline__ void split8(float4 a, float4 b, short8& hi, short8& lo) {
  float v[8] = {a.x, a.y, a.z, a.w, b.x, b.y, b.z, b.w};
#pragma unroll
  for (int j = 0; j < 8; ++j) {
    const __hip_bfloat16 h = __float2bfloat16(v[j]);
    hi[j] = (short)__bfloat16_as_ushort(h);
    const __hip_bfloat16 l = __float2bfloat16(v[j] - __bfloat162float(h));
    lo[j] = (short)__bfloat16_as_ushort(l);
  }
}

// R12 champion + (a) wave-self-contained softmax->GEMV epilogue: drops the
// last 2 block-wide barriers (wave w owns row w end-to-end; weights read
// back from its own LDS row under wave-internal lgkmcnt ordering), and
// (b) mask prefetch hoisted above the score loop so HBM latency hides
// under ~7us of score compute.
__launch_bounds__(kThreads)
__attribute__((amdgpu_waves_per_eu(4, 4)))
__global__ void bahdanau_fused(const float* __restrict__ queries,
                               const float* __restrict__ keys,
                               const float* __restrict__ masks,
                               const float* __restrict__ Wq,
                               const float* __restrict__ bq,
                               const float* __restrict__ Wk,
                               const float* __restrict__ bk,
                               const float* __restrict__ Wv,
                               float* __restrict__ out_attn,
                               float* __restrict__ out_w) {
  extern __shared__ __align__(16) float smem[];
  float* skh = smem;                           // [200][132] Ek
  float* ssc = smem + kKhFloats;               // [16][200] scores -> weights
  float* sqh = smem + kKhFloats + kScFloats;   // [16][128] Eq

  const int tid  = threadIdx.x;
  const int b    = blockIdx.x;
  const int lane = tid & 63;
  const int wave = __builtin_amdgcn_readfirstlane(tid >> 6);   // 0..15
  const int l15  = lane & 15;
  const int q16  = lane >> 4;
  const int hbase = 8 * l15;

  const float* kb = keys + (size_t)b * kNK * kDK;
  const float* qb = queries + (size_t)b * kNQ * kDK;

  // ================== projections on the matrix pipe (as R6/R12) ==================
  {
    const int tc  = wave >> 1;
    const int odd = wave & 1;
    const int col = tc * 16 + l15;
    const int kj0 = q16 * 8;

    short8 bh[2], bl[2];
#pragma unroll
    for (int p = 0; p < 2; ++p) {
      float4 v0, v1;
      v0.x = Wk[(p * 32 + kj0 + 0) * kNH + col];
      v0.y = Wk[(p * 32 + kj0 + 1) * kNH + col];
      v0.z = Wk[(p * 32 + kj0 + 2) * kNH + col];
      v0.w = Wk[(p * 32 + kj0 + 3) * kNH + col];
      v1.x = Wk[(p * 32 + kj0 + 4) * kNH + col];
      v1.y = Wk[(p * 32 + kj0 + 5) * kNH + col];
      v1.z = Wk[(p * 32 + kj0 + 6) * kNH + col];
      v1.w = Wk[(p * 32 + kj0 + 7) * kNH + col];
      split8(v0, v1, bh[p], bl[p]);
    }
    const float bkc = bk[col];

    const int trB = odd ? 7 : 0;
    const int trE = odd ? 13 : 7;
    for (int tr = trB; tr < trE; ++tr) {
      f32x4 acc = {0.f, 0.f, 0.f, 0.f};
      const int row = tr * 16 + l15;
      const bool ok = row < kNK;
#pragma unroll
      for (int p = 0; p < 2; ++p) {
        float4 a0 = {0.f, 0.f, 0.f, 0.f}, a1 = {0.f, 0.f, 0.f, 0.f};
        if (ok) {
          const float* ap = kb + (size_t)row * kDK + p * 32 + kj0;
          a0 = *reinterpret_cast<const float4*>(ap);
          a1 = *reinterpret_cast<const float4*>(ap + 4);
        }
        short8 ah, al;
        split8(a0, a1, ah, al);
        acc = __builtin_amdgcn_mfma_f32_16x16x32_bf16(al, bh[p], acc, 0, 0, 0);
        acc = __builtin_amdgcn_mfma_f32_16x16x32_bf16(ah, bl[p], acc, 0, 0, 0);
        acc = __builtin_amdgcn_mfma_f32_16x16x32_bf16(ah, bh[p], acc, 0, 0, 0);
      }
#pragma unroll
      for (int r = 0; r < 4; ++r) {
        const int rr = tr * 16 + q16 * 4 + r;  // C row = (lane>>4)*4 + reg
        if (rr < kNK) skh[(size_t)rr * kS + col] = exp2_hw(kC2 * (acc[r] + bkc));
      }
    }

    if (odd) {  // query tile
      short8 qbh[2], qbl[2];
#pragma unroll
      for (int p = 0; p < 2; ++p) {
        float4 v0, v1;
        v0.x = Wq[(p * 32 + kj0 + 0) * kNH + col];
        v0.y = Wq[(p * 32 + kj0 + 1) * kNH + col];
        v0.z = Wq[(p * 32 + kj0 + 2) * kNH + col];
        v0.w = Wq[(p * 32 + kj0 + 3) * kNH + col];
        v1.x = Wq[(p * 32 + kj0 + 4) * kNH + col];
        v1.y = Wq[(p * 32 + kj0 + 5) * kNH + col];
        v1.z = Wq[(p * 32 + kj0 + 6) * kNH + col];
        v1.w = Wq[(p * 32 + kj0 + 7) * kNH + col];
        split8(v0, v1, qbh[p], qbl[p]);
      }
      const float bqc = bq[col];
      f32x4 acc = {0.f, 0.f, 0.f, 0.f};
#pragma unroll
      for (int p = 0; p < 2; ++p) {
        const float* ap = qb + (size_t)l15 * kDK + p * 32 + kj0;
        const float4 a0 = *reinterpret_cast<const float4*>(ap);
        const float4 a1 = *reinterpret_cast<const float4*>(ap + 4);
        short8 ah, al;
        split8(a0, a1, ah, al);
        acc = __builtin_amdgcn_mfma_f32_16x16x32_bf16(al, qbh[p], acc, 0, 0, 0);
        acc = __builtin_amdgcn_mfma_f32_16x16x32_bf16(ah, qbl[p], acc, 0, 0, 0);
        acc = __builtin_amdgcn_mfma_f32_16x16x32_bf16(ah, qbh[p], acc, 0, 0, 0);
      }
#pragma unroll
      for (int r = 0; r < 4; ++r)
        sqh[(size_t)(q16 * 4 + r) * kNH + col] = exp2_hw(kC2 * (acc[r] + bqc));
    }
  }

  float wv2[8];
  {
    const float4 wva = *reinterpret_cast<const float4*>(&Wv[hbase]);
    const float4 wvb = *reinterpret_cast<const float4*>(&Wv[hbase + 4]);
    wv2[0] = -2.0f * wva.x; wv2[1] = -2.0f * wva.y;
    wv2[2] = -2.0f * wva.z; wv2[3] = -2.0f * wva.w;
    wv2[4] = -2.0f * wvb.x; wv2[5] = -2.0f * wvb.y;
    wv2[6] = -2.0f * wvb.z; wv2[7] = -2.0f * wvb.w;
  }

  // ---- mask prefetch HOISTED: HBM latency hides under the score loop ----
  const float* mrow = masks + ((size_t)b * kNQ + wave) * kNK;
  const bool tail = lane < (kNK - 192);
  const float mm0 = mrow[lane];
  const float mm1 = mrow[lane + 64];
  const float mm2 = mrow[lane + 128];
  const float mm3 = tail ? mrow[lane + 192] : 0.0f;

  __syncthreads();  // Eq + Ek visible

  const int qg = wave >> 2;
  const int kg = wave & 3;
  float qreg[4][8];
#pragma unroll
  for (int qi = 0; qi < 4; ++qi) {
    const float4 qa  = *reinterpret_cast<const float4*>(&sqh[(4 * qg + qi) * kNH + hbase]);
    const float4 qb4 = *reinterpret_cast<const float4*>(&sqh[(4 * qg + qi) * kNH + hbase + 4]);
    qreg[qi][0] = qa.x;  qreg[qi][1] = qa.y;  qreg[qi][2] = qa.z;  qreg[qi][3] = qa.w;
    qreg[qi][4] = qb4.x; qreg[qi][5] = qb4.y; qreg[qi][6] = qb4.z; qreg[qi][7] = qb4.w;
  }
#pragma unroll
  for (int qi = 0; qi < 4; ++qi)
#pragma unroll
    for (int m = 0; m < 8; ++m) asm volatile("" : "+v"(qreg[qi][m]));  // keep resident

  // ---- score, quad-factorized (1 rcp / 4 elements, as R12) ----
  {
    auto score_k = [&](int k) {
      const float* krow = &skh[(size_t)k * kS + hbase];
      const float4 ka  = *reinterpret_cast<const float4*>(krow);
      const float4 kb4 = *reinterpret_cast<const float4*>(krow + 4);
#pragma unroll
      for (int qi = 0; qi < 4; ++qi) {
        const float uA = fmaf(qreg[qi][0], ka.x, 1.0f);
        const float vA = fmaf(qreg[qi][1], ka.y, 1.0f);
        const float wA = fmaf(qreg[qi][2], ka.z, 1.0f);
        const float xA = fmaf(qreg[qi][3], ka.w, 1.0f);
        const float p1A = uA * vA;
        const float p2A = wA * xA;
        const float n1A = fmaf(wv2[0], vA, wv2[1] * uA);
        const float n2A = fmaf(wv2[2], xA, wv2[3] * wA);
        const float denA = p1A * p2A;
        const float numA = fmaf(n1A, p2A, n2A * p1A);
        const float uB = fmaf(qreg[qi][4], kb4.x, 1.0f);
        const float vB = fmaf(qreg[qi][5], kb4.y, 1.0f);
        const float wB = fmaf(qreg[qi][6], kb4.z, 1.0f);
        const float xB = fmaf(qreg[qi][7], kb4.w, 1.0f);
        const float p1B = uB * vB;
        const float p2B = wB * xB;
        const float n1B = fmaf(wv2[4], vB, wv2[5] * uB);
        const float n2B = fmaf(wv2[6], xB, wv2[7] * wB);
        const float denB = p1B * p2B;
        const float numB = fmaf(n1B, p2B, n2B * p1B);
        const float rA = __builtin_amdgcn_rcpf(denA);
        const float rB = __builtin_amdgcn_rcpf(denB);
        float acc = fmaf(numB, rB, numA * rA);
        acc = dpp_add<0xB1>(acc);   // xor 1
        acc = dpp_add<0x4E>(acc);   // xor 2
        acc = dpp_add<0x141>(acc);  // row_half_mirror (8-fold)
        acc = dpp_add<0x140>(acc);  // row_mirror (16-fold)
        if (l15 == 0) ssc[(4 * qg + qi) * kNK + k] = acc;
      }
    };
    for (int i = 0; i < 12; ++i) score_k(16 * i + 4 * kg + q16);
    if (kg < 2) score_k(192 + 4 * kg + q16);  // tail k=192..199
  }

  __syncthreads();  // scores visible (the LAST block-wide barrier)

  // ---- softmax + full GEMV, wave-self-contained (no more barriers) ----
  {
    float* swr = &ssc[wave * kNK];
    float v0 = fmaf(mm0, kNeg, swr[lane]);
    float v1 = fmaf(mm1, kNeg, swr[lane + 64]);
    float v2 = fmaf(mm2, kNeg, swr[lane + 128]);
    float v3 = tail ? fmaf(mm3, kNeg, swr[lane + 192]) : -1e30f;
    float m = fmaxf(fmaxf(v0, v1), fmaxf(v2, v3));
#pragma unroll
    for (int off = 32; off > 0; off >>= 1) m = fmaxf(m, __shfl_xor(m, off, 64));
    const float e0 = __expf(v0 - m);
    const float e1 = __expf(v1 - m);
    const float e2 = __expf(v2 - m);
    const float e3 = tail ? __expf(v3 - m) : 0.f;
    float sum = (e0 + e1) + (e2 + e3);
#pragma unroll
    for (int off = 32; off > 0; off >>= 1) sum += __shfl_xor(sum, off, 64);
    const float rs = __builtin_amdgcn_rcpf(sum);
    float* og = out_w + ((size_t)b * kNQ + wave) * kNK;
    const float w0 = e0 * rs, w1 = e1 * rs, w2 = e2 * rs, w3 = e3 * rs;
    swr[lane]       = w0;  og[lane]       = w0;
    swr[lane + 64]  = w1;  og[lane + 64]  = w1;
    swr[lane + 128] = w2;  og[lane + 128] = w2;
    if (tail) { swr[lane + 192] = w3; og[lane + 192] = w3; }

    // Wave w's own full GEMV: reads back its own LDS row (wave-internal
    // lgkmcnt ordering, no barrier); keys rows are L2-hot from projection.
    const float* kb2 = kb + lane;  // d = lane
    float a0 = 0.f, a1 = 0.f, a2 = 0.f, a3 = 0.f;
#pragma unroll 2
    for (int k0 = 0; k0 < kNK; k0 += 4) {
      const float4 wq = *reinterpret_cast<const float4*>(&swr[k0]);  // broadcast
      a0 = fmaf(wq.x, kb2[(size_t)(k0 + 0) * kDK], a0);
      a1 = fmaf(wq.y, kb2[(size_t)(k0 + 1) * kDK], a1);
      a2 = fmaf(wq.z, kb2[(size_t)(k0 + 2) * kDK], a2);
      a3 = fmaf(wq.w, kb2[(size_t)(k0 + 3) * kDK], a3);
    }
    out_attn[((size_t)b * kNQ + wave) * kDK + lane] = (a0 + a1) + (a2 + a3);
  }
}

}  // namespace

extern "C" void kernel_launch(void* const* d_in, const int* in_sizes, int n_in,
                              void* d_out, int out_size, void* d_ws, size_t ws_size,
                              hipStream_t stream) {
  const float* queries = (const float*)d_in[0];
  const float* keys    = (const float*)d_in[1];
  const float* masks   = (const float*)d_in[2];
  // d_in[3] = num_neg (unused)
  const float* Wq = (const float*)d_in[4];
  const float* bq = (const float*)d_in[5];
  const float* Wk = (const float*)d_in[6];
  const float* bk = (const float*)d_in[7];
  const float* Wv = (const float*)d_in[8];
  // d_in[9] = bv: softmax-invariant, dropped

  float* out_attn = (float*)d_out;                       // (B, NQ, 64)
  float* out_w    = out_attn + (size_t)kNB * kNQ * kDK;  // (B, NQ, 200, 1)

  hipFuncSetAttribute((const void*)bahdanau_fused,
                      hipFuncAttributeMaxDynamicSharedMemorySize, (int)kSmemBytes);
  bahdanau_fused<<<kNB, kThreads, kSmemBytes, stream>>>(queries, keys, masks, Wq, bq,
                                                        Wk, bk, Wv, out_attn, out_w);
}

// Round 14
// 35.840 us; speedup vs baseline: 1.1080x; 1.1080x over previous
//
#include <hip/hip_runtime.h>
#include <hip/hip_bf16.h>

namespace {

typedef __attribute__((ext_vector_type(8))) short short8;  // 8 bf16 = 4 VGPR
typedef __attribute__((ext_vector_type(4))) float f32x4;   // MFMA accumulator

constexpr int kNB = 256;   // batch
constexpr int kNQ = 16;    // queries per batch
constexpr int kNK = 200;   // keys per batch
constexpr int kDK = 64;    // key/query feature size
constexpr int kNH = 128;   // hidden
constexpr int kThreads = 1024;  // 16 waves
constexpr int kS = 132;         // Ek row stride in floats
constexpr float kNeg = -1000000000.0f;
constexpr float kC2 = 2.8853900817779268f;  // 2*log2(e): exp(2x)=exp2(kC2*x)

constexpr int kKhFloats = kNK * kS;   // 105600 B
constexpr int kScFloats = kNQ * kNK;  // 12800 B
constexpr int kQhFloats = kNQ * kNH;  //  8192 B
constexpr size_t kSmemBytes =
    (size_t)(kKhFloats + kScFloats + kQhFloats) * sizeof(float);  // 126592 B

__device__ __forceinline__ float exp2_hw(float x) {
#if defined(__has_builtin)
# if __has_builtin(__builtin_amdgcn_exp2f)
  return __builtin_amdgcn_exp2f(x);
# else
  return __expf(x * 0.69314718055994531f);
# endif
#else
  return __expf(x * 0.69314718055994531f);
#endif
}

template <int CTRL>
__device__ __forceinline__ float dpp_add(float v) {
  int sw = __builtin_amdgcn_update_dpp(0, __float_as_int(v), CTRL, 0xF, 0xF, true);
  return v + __int_as_float(sw);
}

// split-bf16 via hip casts (compiler packs v_cvt_pk_bf16_f32)
__device__ __forceinline__ void split8(float4 a, float4 b, short8& hi, short8& lo) {
  float v[8] = {a.x, a.y, a.z, a.w, b.x, b.y, b.z, b.w};
#pragma unroll
  for (int j = 0; j < 8; ++j) {
    const __hip_bfloat16 h = __float2bfloat16(v[j]);
    hi[j] = (short)__bfloat16_as_ushort(h);
    const __hip_bfloat16 l = __float2bfloat16(v[j] - __bfloat162float(h));
    lo[j] = (short)__bfloat16_as_ushort(l);
  }
}

// R12 champion + mask-prefetch hoist + no-max softmax. Split-k epilogue and
// both trailing barriers restored from R12 (R13's self-GEMV quadrupled
// epilogue key traffic and regressed).
__launch_bounds__(kThreads)
__attribute__((amdgpu_waves_per_eu(4, 4)))
__global__ void bahdanau_fused(const float* __restrict__ queries,
                               const float* __restrict__ keys,
                               const float* __restrict__ masks,
                               const float* __restrict__ Wq,
                               const float* __restrict__ bq,
                               const float* __restrict__ Wk,
                               const float* __restrict__ bk,
                               const float* __restrict__ Wv,
                               float* __restrict__ out_attn,
                               float* __restrict__ out_w) {
  extern __shared__ __align__(16) float smem[];
  float* skh = smem;                           // [200][132] Ek (later: partials)
  float* ssc = smem + kKhFloats;               // [16][200] scores -> weights
  float* sqh = smem + kKhFloats + kScFloats;   // [16][128] Eq

  const int tid  = threadIdx.x;
  const int b    = blockIdx.x;
  const int lane = tid & 63;
  const int wave = __builtin_amdgcn_readfirstlane(tid >> 6);   // 0..15
  const int l15  = lane & 15;
  const int q16  = lane >> 4;
  const int hbase = 8 * l15;

  const float* kb = keys + (size_t)b * kNK * kDK;
  const float* qb = queries + (size_t)b * kNQ * kDK;

  // ================== projections on the matrix pipe (as R6/R12) ==================
  {
    const int tc  = wave >> 1;
    const int odd = wave & 1;
    const int col = tc * 16 + l15;
    const int kj0 = q16 * 8;

    short8 bh[2], bl[2];
#pragma unroll
    for (int p = 0; p < 2; ++p) {
      float4 v0, v1;
      v0.x = Wk[(p * 32 + kj0 + 0) * kNH + col];
      v0.y = Wk[(p * 32 + kj0 + 1) * kNH + col];
      v0.z = Wk[(p * 32 + kj0 + 2) * kNH + col];
      v0.w = Wk[(p * 32 + kj0 + 3) * kNH + col];
      v1.x = Wk[(p * 32 + kj0 + 4) * kNH + col];
      v1.y = Wk[(p * 32 + kj0 + 5) * kNH + col];
      v1.z = Wk[(p * 32 + kj0 + 6) * kNH + col];
      v1.w = Wk[(p * 32 + kj0 + 7) * kNH + col];
      split8(v0, v1, bh[p], bl[p]);
    }
    const float bkc = bk[col];

    const int trB = odd ? 7 : 0;
    const int trE = odd ? 13 : 7;
    for (int tr = trB; tr < trE; ++tr) {
      f32x4 acc = {0.f, 0.f, 0.f, 0.f};
      const int row = tr * 16 + l15;
      const bool ok = row < kNK;
#pragma unroll
      for (int p = 0; p < 2; ++p) {
        float4 a0 = {0.f, 0.f, 0.f, 0.f}, a1 = {0.f, 0.f, 0.f, 0.f};
        if (ok) {
          const float* ap = kb + (size_t)row * kDK + p * 32 + kj0;
          a0 = *reinterpret_cast<const float4*>(ap);
          a1 = *reinterpret_cast<const float4*>(ap + 4);
        }
        short8 ah, al;
        split8(a0, a1, ah, al);
        acc = __builtin_amdgcn_mfma_f32_16x16x32_bf16(al, bh[p], acc, 0, 0, 0);
        acc = __builtin_amdgcn_mfma_f32_16x16x32_bf16(ah, bl[p], acc, 0, 0, 0);
        acc = __builtin_amdgcn_mfma_f32_16x16x32_bf16(ah, bh[p], acc, 0, 0, 0);
      }
#pragma unroll
      for (int r = 0; r < 4; ++r) {
        const int rr = tr * 16 + q16 * 4 + r;  // C row = (lane>>4)*4 + reg
        if (rr < kNK) skh[(size_t)rr * kS + col] = exp2_hw(kC2 * (acc[r] + bkc));
      }
    }

    if (odd) {  // query tile
      short8 qbh[2], qbl[2];
#pragma unroll
      for (int p = 0; p < 2; ++p) {
        float4 v0, v1;
        v0.x = Wq[(p * 32 + kj0 + 0) * kNH + col];
        v0.y = Wq[(p * 32 + kj0 + 1) * kNH + col];
        v0.z = Wq[(p * 32 + kj0 + 2) * kNH + col];
        v0.w = Wq[(p * 32 + kj0 + 3) * kNH + col];
        v1.x = Wq[(p * 32 + kj0 + 4) * kNH + col];
        v1.y = Wq[(p * 32 + kj0 + 5) * kNH + col];
        v1.z = Wq[(p * 32 + kj0 + 6) * kNH + col];
        v1.w = Wq[(p * 32 + kj0 + 7) * kNH + col];
        split8(v0, v1, qbh[p], qbl[p]);
      }
      const float bqc = bq[col];
      f32x4 acc = {0.f, 0.f, 0.f, 0.f};
#pragma unroll
      for (int p = 0; p < 2; ++p) {
        const float* ap = qb + (size_t)l15 * kDK + p * 32 + kj0;
        const float4 a0 = *reinterpret_cast<const float4*>(ap);
        const float4 a1 = *reinterpret_cast<const float4*>(ap + 4);
        short8 ah, al;
        split8(a0, a1, ah, al);
        acc = __builtin_amdgcn_mfma_f32_16x16x32_bf16(al, qbh[p], acc, 0, 0, 0);
        acc = __builtin_amdgcn_mfma_f32_16x16x32_bf16(ah, qbl[p], acc, 0, 0, 0);
        acc = __builtin_amdgcn_mfma_f32_16x16x32_bf16(ah, qbh[p], acc, 0, 0, 0);
      }
#pragma unroll
      for (int r = 0; r < 4; ++r)
        sqh[(size_t)(q16 * 4 + r) * kNH + col] = exp2_hw(kC2 * (acc[r] + bqc));
    }
  }

  float wv2[8];
  {
    const float4 wva = *reinterpret_cast<const float4*>(&Wv[hbase]);
    const float4 wvb = *reinterpret_cast<const float4*>(&Wv[hbase + 4]);
    wv2[0] = -2.0f * wva.x; wv2[1] = -2.0f * wva.y;
    wv2[2] = -2.0f * wva.z; wv2[3] = -2.0f * wva.w;
    wv2[4] = -2.0f * wvb.x; wv2[5] = -2.0f * wvb.y;
    wv2[6] = -2.0f * wvb.z; wv2[7] = -2.0f * wvb.w;
  }

  // ---- mask prefetch HOISTED: HBM latency hides under the score loop ----
  const float* mrow = masks + ((size_t)b * kNQ + wave) * kNK;
  const bool tail = lane < (kNK - 192);
  const float mm0 = mrow[lane];
  const float mm1 = mrow[lane + 64];
  const float mm2 = mrow[lane + 128];
  const float mm3 = tail ? mrow[lane + 192] : 0.0f;

  __syncthreads();  // Eq + Ek visible

  const int qg = wave >> 2;
  const int kg = wave & 3;
  float qreg[4][8];
#pragma unroll
  for (int qi = 0; qi < 4; ++qi) {
    const float4 qa  = *reinterpret_cast<const float4*>(&sqh[(4 * qg + qi) * kNH + hbase]);
    const float4 qb4 = *reinterpret_cast<const float4*>(&sqh[(4 * qg + qi) * kNH + hbase + 4]);
    qreg[qi][0] = qa.x;  qreg[qi][1] = qa.y;  qreg[qi][2] = qa.z;  qreg[qi][3] = qa.w;
    qreg[qi][4] = qb4.x; qreg[qi][5] = qb4.y; qreg[qi][6] = qb4.z; qreg[qi][7] = qb4.w;
  }
#pragma unroll
  for (int qi = 0; qi < 4; ++qi)
#pragma unroll
    for (int m = 0; m < 8; ++m) asm volatile("" : "+v"(qreg[qi][m]));  // keep resident

  // ---- score, quad-factorized (1 rcp / 4 elements, as R12) ----
  {
    auto score_k = [&](int k) {
      const float* krow = &skh[(size_t)k * kS + hbase];
      const float4 ka  = *reinterpret_cast<const float4*>(krow);
      const float4 kb4 = *reinterpret_cast<const float4*>(krow + 4);
#pragma unroll
      for (int qi = 0; qi < 4; ++qi) {
        const float uA = fmaf(qreg[qi][0], ka.x, 1.0f);
        const float vA = fmaf(qreg[qi][1], ka.y, 1.0f);
        const float wA = fmaf(qreg[qi][2], ka.z, 1.0f);
        const float xA = fmaf(qreg[qi][3], ka.w, 1.0f);
        const float p1A = uA * vA;
        const float p2A = wA * xA;
        const float n1A = fmaf(wv2[0], vA, wv2[1] * uA);
        const float n2A = fmaf(wv2[2], xA, wv2[3] * wA);
        const float denA = p1A * p2A;
        const float numA = fmaf(n1A, p2A, n2A * p1A);
        const float uB = fmaf(qreg[qi][4], kb4.x, 1.0f);
        const float vB = fmaf(qreg[qi][5], kb4.y, 1.0f);
        const float wB = fmaf(qreg[qi][6], kb4.z, 1.0f);
        const float xB = fmaf(qreg[qi][7], kb4.w, 1.0f);
        const float p1B = uB * vB;
        const float p2B = wB * xB;
        const float n1B = fmaf(wv2[4], vB, wv2[5] * uB);
        const float n2B = fmaf(wv2[6], xB, wv2[7] * wB);
        const float denB = p1B * p2B;
        const float numB = fmaf(n1B, p2B, n2B * p1B);
        const float rA = __builtin_amdgcn_rcpf(denA);
        const float rB = __builtin_amdgcn_rcpf(denB);
        float acc = fmaf(numB, rB, numA * rA);
        acc = dpp_add<0xB1>(acc);   // xor 1
        acc = dpp_add<0x4E>(acc);   // xor 2
        acc = dpp_add<0x141>(acc);  // row_half_mirror (8-fold)
        acc = dpp_add<0x140>(acc);  // row_mirror (16-fold)
        if (l15 == 0) ssc[(4 * qg + qi) * kNK + k] = acc;
      }
    };
    for (int i = 0; i < 12; ++i) score_k(16 * i + 4 * kg + q16);
    if (kg < 2) score_k(192 + 4 * kg + q16);  // tail k=192..199
  }

  __syncthreads();  // scores visible

  // ---- softmax over k, NO max-subtract: unmasked scores bounded (|s|<~9,
  //      exp in [1e-4,8e3], f32-safe); masked -> exp(-1e9) underflows to 0 ----
  {
    const float* sr = &ssc[wave * kNK];
    const float e0 = __expf(fmaf(mm0, kNeg, sr[lane]));
    const float e1 = __expf(fmaf(mm1, kNeg, sr[lane + 64]));
    const float e2 = __expf(fmaf(mm2, kNeg, sr[lane + 128]));
    const float e3 = tail ? __expf(fmaf(mm3, kNeg, sr[lane + 192])) : 0.f;
    float sum = (e0 + e1) + (e2 + e3);
#pragma unroll
    for (int off = 32; off > 0; off >>= 1) sum += __shfl_xor(sum, off, 64);
    const float rs = __builtin_amdgcn_rcpf(sum);
    float* og = out_w + ((size_t)b * kNQ + wave) * kNK;
    float* swr = &ssc[wave * kNK];
    const float w0 = e0 * rs, w1 = e1 * rs, w2 = e2 * rs, w3 = e3 * rs;
    swr[lane]       = w0;  og[lane]       = w0;
    swr[lane + 64]  = w1;  og[lane + 64]  = w1;
    swr[lane + 128] = w2;  og[lane + 128] = w2;
    if (tail) { swr[lane + 192] = w3; og[lane + 192] = w3; }
  }
  __syncthreads();  // weights visible; skh dead -> reuse for partials

  // ---- epilogue: wave (qg,kg) partial GEMV over its k-range (R12) ----
  {
    float* pk = skh;  // [16][4][64] partials
    const int kstart = 52 * kg;
    const int kend = (kg == 3) ? kNK : (kstart + 52);
    const float* kb2 = kb + lane;  // d = lane
    float acc[4] = {0.f, 0.f, 0.f, 0.f};
    for (int k0 = kstart; k0 < kend; k0 += 4) {
      const float kv0 = kb2[(size_t)(k0 + 0) * kDK];
      const float kv1 = kb2[(size_t)(k0 + 1) * kDK];
      const float kv2 = kb2[(size_t)(k0 + 2) * kDK];
      const float kv3 = kb2[(size_t)(k0 + 3) * kDK];
#pragma unroll
      for (int qi = 0; qi < 4; ++qi) {
        const float4 wq = *reinterpret_cast<const float4*>(&ssc[(4 * qg + qi) * kNK + k0]);
        acc[qi] = fmaf(wq.x, kv0, acc[qi]);
        acc[qi] = fmaf(wq.y, kv1, acc[qi]);
        acc[qi] = fmaf(wq.z, kv2, acc[qi]);
        acc[qi] = fmaf(wq.w, kv3, acc[qi]);
      }
    }
#pragma unroll
    for (int qi = 0; qi < 4; ++qi)
      pk[((4 * qg + qi) * 4 + kg) * kDK + lane] = acc[qi];
  }
  __syncthreads();

  // ---- final combine ----
  {
    const float* pk = skh;
    const float r = pk[(wave * 4 + 0) * kDK + lane] + pk[(wave * 4 + 1) * kDK + lane] +
                    pk[(wave * 4 + 2) * kDK + lane] + pk[(wave * 4 + 3) * kDK + lane];
    out_attn[((size_t)b * kNQ + wave) * kDK + lane] = r;
  }
}

}  // namespace

extern "C" void kernel_launch(void* const* d_in, const int* in_sizes, int n_in,
                              void* d_out, int out_size, void* d_ws, size_t ws_size,
                              hipStream_t stream) {
  const float* queries = (const float*)d_in[0];
  const float* keys    = (const float*)d_in[1];
  const float* masks   = (const float*)d_in[2];
  // d_in[3] = num_neg (unused)
  const float* Wq = (const float*)d_in[4];
  const float* bq = (const float*)d_in[5];
  const float* Wk = (const float*)d_in[6];
  const float* bk = (const float*)d_in[7];
  const float* Wv = (const float*)d_in[8];
  // d_in[9] = bv: softmax-invariant, dropped

  float* out_attn = (float*)d_out;                       // (B, NQ, 64)
  float* out_w    = out_attn + (size_t)kNB * kNQ * kDK;  // (B, NQ, 200, 1)

  hipFuncSetAttribute((const void*)bahdanau_fused,
                      hipFuncAttributeMaxDynamicSharedMemorySize, (int)kSmemBytes);
  bahdanau_fused<<<kNB, kThreads, kSmemBytes, stream>>>(queries, keys, masks, Wq, bq,
                                                        Wk, bk, Wv, out_attn, out_w);
}